// Round 5
// baseline (173.263 us; speedup 1.0000x reference)
//
#include <hip/hip_runtime.h>

#define NTYPES 6
#define HID 128
#define E_TILE 64

typedef short short8 __attribute__((ext_vector_type(8)));
typedef float f32x4 __attribute__((ext_vector_type(4)));

static __device__ __forceinline__ ushort f2bf(float f) {
    union { float f; unsigned u; } v; v.f = f;
    unsigned r = v.u + 0x7FFFu + ((v.u >> 16) & 1u);   // RNE
    return (ushort)(r >> 16);
}

// ---------------- binning ----------------

// fused: per-block LDS type histogram + per-tgt-node arrival rank
__global__ void k_pass1(const int* __restrict__ etype, const int* __restrict__ tgt,
                        int E, int* __restrict__ cnts,
                        int* __restrict__ ncnt, int* __restrict__ arr) {
    __shared__ int h[NTYPES];
    if (threadIdx.x < NTYPES) h[threadIdx.x] = 0;
    __syncthreads();
    int i = blockIdx.x * blockDim.x + threadIdx.x;
    if (i < E) {
        atomicAdd(&h[etype[i] - 1], 1);
        arr[i] = atomicAdd(&ncnt[tgt[i]], 1);
    }
    __syncthreads();
    if (threadIdx.x < NTYPES) {
        int c = h[threadIdx.x];
        if (c) atomicAdd(&cnts[threadIdx.x], c);
    }
}

// hist-only (atomic fallback path)
__global__ void k_hist(const int* __restrict__ etype, int E, int* __restrict__ cnts) {
    __shared__ int h[NTYPES];
    if (threadIdx.x < NTYPES) h[threadIdx.x] = 0;
    __syncthreads();
    int i = blockIdx.x * blockDim.x + threadIdx.x;
    if (i < E) atomicAdd(&h[etype[i] - 1], 1);
    __syncthreads();
    if (threadIdx.x < NTYPES) {
        int c = h[threadIdx.x];
        if (c) atomicAdd(&cnts[threadIdx.x], c);
    }
}

__global__ void k_prefix(int* __restrict__ ws) {
    if (threadIdx.x == 0 && blockIdx.x == 0) {
        int acc = 0;
        for (int t = 0; t < NTYPES; ++t) { ws[8 + t] = acc; acc += ws[t]; }
        ws[8 + NTYPES] = acc;
    }
}

__global__ void k_fill(const int* __restrict__ etype, int E, int* __restrict__ ws,
                       int* __restrict__ sorted) {
    __shared__ int lcnt[NTYPES];
    __shared__ int lbase[NTYPES];
    if (threadIdx.x < NTYPES) lcnt[threadIdx.x] = 0;
    __syncthreads();
    int i = blockIdx.x * blockDim.x + threadIdx.x;
    int t = 0, lr = 0;
    bool valid = (i < E);
    if (valid) {
        t = etype[i] - 1;
        lr = atomicAdd(&lcnt[t], 1);
    }
    __syncthreads();
    if (threadIdx.x < NTYPES) {
        int c = lcnt[threadIdx.x];
        lbase[threadIdx.x] = c ? atomicAdd(&ws[16 + threadIdx.x], c) : 0;
    }
    __syncthreads();
    if (valid) sorted[ws[8 + t] + lbase[t] + lr] = i;
}

// ---------------- node-offset scan ----------------

__global__ void k_scan1(const int* __restrict__ ncnt, int* __restrict__ noff,
                        int* __restrict__ bsum, int N) {
    __shared__ int s[256];
    const int b = blockIdx.x, t = threadIdx.x;
    const int base = b * 1024 + t * 4;
    int v[4];
    #pragma unroll
    for (int i = 0; i < 4; ++i) v[i] = (base + i < N) ? ncnt[base + i] : 0;
    int tsum = v[0] + v[1] + v[2] + v[3];
    s[t] = tsum;
    __syncthreads();
    for (int off = 1; off < 256; off <<= 1) {
        int x = (t >= off) ? s[t - off] : 0;
        __syncthreads();
        s[t] += x;
        __syncthreads();
    }
    if (t == 255) bsum[b] = s[255];
    int run = s[t] - tsum;
    #pragma unroll
    for (int i = 0; i < 4; ++i)
        if (base + i < N) { noff[base + i] = run; run += v[i]; }
}

__global__ void k_scan2(int* __restrict__ bsum, int nb) {
    __shared__ int s[256];
    const int t = threadIdx.x;
    int v = (t < nb) ? bsum[t] : 0;
    s[t] = v;
    __syncthreads();
    for (int off = 1; off < 256; off <<= 1) {
        int x = (t >= off) ? s[t - off] : 0;
        __syncthreads();
        s[t] += x;
        __syncthreads();
    }
    if (t < nb) bsum[t] = s[t] - v;   // exclusive
}

__global__ void k_scan3(int* __restrict__ noff, const int* __restrict__ bsum,
                        int N, int E) {
    int i = blockIdx.x * blockDim.x + threadIdx.x;
    if (i < N) noff[i] += bsum[i >> 10];
    if (i == 0) noff[N] = E;
}

// ---------------- conversions (fused: state f32->bf16, W transpose+convert) ----------------

__global__ void k_conv(const float* __restrict__ Sf, ushort* __restrict__ Sb, int total,
                       const float* __restrict__ W, ushort* __restrict__ Wt, int sblocks) {
    int b = blockIdx.x;
    if (b < sblocks) {
        int g = (b * 256 + threadIdx.x) * 8;
        if (g < total) {
            float4 a = *(const float4*)(Sf + g);
            float4 c = *(const float4*)(Sf + g + 4);
            ushort t[8] = { f2bf(a.x), f2bf(a.y), f2bf(a.z), f2bf(a.w),
                            f2bf(c.x), f2bf(c.y), f2bf(c.z), f2bf(c.w) };
            *(short8*)(Sb + g) = *(short8*)t;
        }
    } else {
        int t = (b - sblocks) * 256 + threadIdx.x;
        int n  = t & 127;
        int k8 = (t >> 7) & 31;
        int ty = t >> 12;
        if (ty >= NTYPES) return;
        const float* wp = W + ((size_t)ty * 256 + (size_t)k8 * 8) * HID + n;
        ushort tmp[8];
        #pragma unroll
        for (int j = 0; j < 8; ++j) tmp[j] = f2bf(wp[(size_t)j * HID]);
        *(short8*)(Wt + ((size_t)ty * HID + n) * 256 + k8 * 8) = *(short8*)tmp;
    }
}

// W-only conversion (fallback paths)
__global__ void k_wconv(const float* __restrict__ W, ushort* __restrict__ Wt) {
    int t = blockIdx.x * blockDim.x + threadIdx.x;
    int n  = t & 127;
    int k8 = (t >> 7) & 31;
    int ty = t >> 12;
    if (ty >= NTYPES) return;
    const float* wp = W + ((size_t)ty * 256 + (size_t)k8 * 8) * HID + n;
    ushort tmp[8];
    #pragma unroll
    for (int j = 0; j < 8; ++j) tmp[j] = f2bf(wp[(size_t)j * HID]);
    *(short8*)(Wt + ((size_t)ty * HID + n) * 256 + k8 * 8) = *(short8*)tmp;
}

// ---------------- GEMM ----------------
// MODE 2: bf16 state gather, msgs write (no atomics)
// MODE 1: f32 state gather, msgs write (no atomics)
// MODE 0: f32 state gather, atomic scatter into out
template <int MODE>
__launch_bounds__(256, 4)
__global__ void k_edge_gemm(const float* __restrict__ Sf,
                            const ushort* __restrict__ Sb,
                            const int* __restrict__ src,
                            const int* __restrict__ tgt,
                            const ushort* __restrict__ Wt,
                            const int* __restrict__ hdr,
                            const int* __restrict__ sorted,
                            const int* __restrict__ noff,
                            const int* __restrict__ arr,
                            ushort* __restrict__ msgs,
                            float* __restrict__ out) {
    __shared__ __align__(16) ushort Xs[E_TILE][264];   // 33792 B
    __shared__ int sN[E_TILE];
    __shared__ int tN[E_TILE];
    __shared__ int dstR[E_TILE];

    const int* offs = hdr + 8;

    int tile = blockIdx.x;
    int ty, base = 0, cnt = 0;
    for (ty = 0; ty < NTYPES; ++ty) {
        int b = offs[ty], oend = offs[ty + 1];
        int nt = (oend - b + E_TILE - 1) / E_TILE;
        if (tile < nt) {
            base = b + tile * E_TILE;
            cnt = oend - base;
            if (cnt > E_TILE) cnt = E_TILE;
            break;
        }
        tile -= nt;
    }
    if (ty == NTYPES) return;

    const int tid = threadIdx.x;
    const int w  = tid >> 6;
    const int l  = tid & 63;
    const int lr = l & 15;
    const int lg = l >> 4;

    if (tid < E_TILE) {
        int sn = 0, tn = 0, dr = 0;
        if (tid < cnt) {
            int e = sorted[base + tid];
            sn = src[e]; tn = tgt[e];
            if (MODE >= 1) dr = noff[tn] + arr[e];
        }
        sN[tid] = sn; tN[tid] = tn; dstR[tid] = dr;
    }

    // prefetch all W fragments for this wave into registers (in flight under staging)
    short8 wreg[16];
    {
        const ushort* wb = Wt + ((size_t)ty * HID + w * 32 + lr) * 256 + 8 * lg;
        #pragma unroll
        for (int kk = 0; kk < 8; ++kk) {
            wreg[2 * kk]     = *(const short8*)(wb + kk * 32);
            wreg[2 * kk + 1] = *(const short8*)(wb + 16 * 256 + kk * 32);
        }
    }
    __syncthreads();

    // ---- stage X = [state[src] | state[tgt]] as bf16 [64][256] ----
    if (MODE == 2) {
        const int e = tid >> 2, q = tid & 3;           // 4 threads/edge, 64 ushorts each
        if (e < cnt) {
            const int node = (q & 2) ? tN[e] : sN[e];
            const ushort* rp = Sb + (size_t)node * HID + (q & 1) * 64;
            short8 v[8];
            #pragma unroll
            for (int i = 0; i < 8; ++i) v[i] = *(const short8*)(rp + i * 8);
            ushort* dp = &Xs[e][q * 64];
            #pragma unroll
            for (int i = 0; i < 8; ++i) *(short8*)(dp + i * 8) = v[i];
        } else {
            short8 z = (short8){0, 0, 0, 0, 0, 0, 0, 0};
            ushort* dp = &Xs[e][q * 64];
            #pragma unroll
            for (int i = 0; i < 8; ++i) *(short8*)(dp + i * 8) = z;
        }
    } else {
        const int e = tid >> 2, q = tid & 3;
        if (e < cnt) {
            #pragma unroll
            for (int h = 0; h < 2; ++h) {
                const int node = h ? tN[e] : sN[e];
                const float* rp = Sf + (size_t)node * HID + q * 32;
                #pragma unroll
                for (int i = 0; i < 4; ++i) {
                    float4 v0 = *(const float4*)(rp + i * 8);
                    float4 v1 = *(const float4*)(rp + i * 8 + 4);
                    ushort tmp[8] = { f2bf(v0.x), f2bf(v0.y), f2bf(v0.z), f2bf(v0.w),
                                      f2bf(v1.x), f2bf(v1.y), f2bf(v1.z), f2bf(v1.w) };
                    *(short8*)&Xs[e][h * HID + q * 32 + i * 8] = *(short8*)tmp;
                }
            }
        } else {
            short8 z = (short8){0, 0, 0, 0, 0, 0, 0, 0};
            #pragma unroll
            for (int h = 0; h < 2; ++h)
                #pragma unroll
                for (int i = 0; i < 4; ++i)
                    *(short8*)&Xs[e][h * HID + q * 32 + i * 8] = z;
        }
    }
    __syncthreads();

    f32x4 acc[4][2];
    #pragma unroll
    for (int mf = 0; mf < 4; ++mf)
        #pragma unroll
        for (int nf = 0; nf < 2; ++nf)
            acc[mf][nf] = (f32x4){0.f, 0.f, 0.f, 0.f};

    const ushort* xb = &Xs[lr][8 * lg];
    #pragma unroll
    for (int kk = 0; kk < 8; ++kk) {
        const int k0 = kk * 32;
        #pragma unroll
        for (int mf = 0; mf < 4; ++mf) {
            short8 a = *(const short8*)(xb + mf * 16 * 264 + k0);
            acc[mf][0] = __builtin_amdgcn_mfma_f32_16x16x32_bf16(a, wreg[2 * kk],     acc[mf][0], 0, 0, 0);
            acc[mf][1] = __builtin_amdgcn_mfma_f32_16x16x32_bf16(a, wreg[2 * kk + 1], acc[mf][1], 0, 0, 0);
        }
    }

    // ---- epilogue ----
    __syncthreads();
    float (*Os)[132] = (float (*)[132])&Xs[0][0];   // 64*132*4 = 33792 B exactly
    #pragma unroll
    for (int mf = 0; mf < 4; ++mf)
        #pragma unroll
        for (int nf = 0; nf < 2; ++nf)
            #pragma unroll
            for (int r = 0; r < 4; ++r)
                Os[mf * 16 + lg * 4 + r][w * 32 + nf * 16 + lr] = acc[mf][nf][r];
    __syncthreads();

    if (MODE >= 1) {
        const int r8 = tid >> 4, cg = tid & 15;
        #pragma unroll
        for (int rr = 0; rr < 4; ++rr) {
            int row = rr * 16 + r8;
            if (row < cnt) {
                float4 a = *(const float4*)&Os[row][cg * 8];
                float4 b = *(const float4*)&Os[row][cg * 8 + 4];
                ushort tmp[8] = { f2bf(a.x), f2bf(a.y), f2bf(a.z), f2bf(a.w),
                                  f2bf(b.x), f2bf(b.y), f2bf(b.z), f2bf(b.w) };
                *(short8*)(msgs + (size_t)dstR[row] * HID + cg * 8) = *(short8*)tmp;
            }
        }
    } else {
        const int erow = tid >> 7;
        const int c    = tid & (HID - 1);
        for (int it = 0; it < E_TILE / 2; ++it) {
            int ee = it * 2 + erow;
            if (ee < cnt) atomicAdd(&out[(size_t)tN[ee] * HID + c], Os[ee][c]);
        }
    }
}

// each 64-lane group owns one node: sum msgs rows [noff[n],noff[n+1]), write once
__launch_bounds__(256)
__global__ void k_scatter(const ushort* __restrict__ msgs, const int* __restrict__ noff,
                          float* __restrict__ out, int N) {
    int node = blockIdx.x * 4 + (threadIdx.x >> 6);
    if (node >= N) return;
    int cp = threadIdx.x & 63;                 // column pair
    int s = noff[node], e = noff[node + 1];
    float a0 = 0.f, a1 = 0.f;
    for (int r = s; r < e; ++r) {
        unsigned u = *(const unsigned*)(msgs + (size_t)r * HID + cp * 2);
        union { unsigned u; float f; } lo, hi;
        lo.u = u << 16; hi.u = u & 0xFFFF0000u;
        a0 += lo.f; a1 += hi.f;
    }
    *(float2*)(out + (size_t)node * HID + cp * 2) = make_float2(a0, a1);
}

extern "C" void kernel_launch(void* const* d_in, const int* in_sizes, int n_in,
                              void* d_out, int out_size, void* d_ws, size_t ws_size,
                              hipStream_t stream) {
    const float* Sf    = (const float*)d_in[0];
    const int*   edges = (const int*)d_in[1];
    const float* W     = (const float*)d_in[2];
    float* out = (float*)d_out;

    const int E = in_sizes[1] / 3;
    const int N = in_sizes[0] / HID;
    const int* etype = edges;
    const int* src   = edges + E;
    const int* tgt   = edges + 2 * E;
    int* ws = (int*)d_ws;

    // layout: hdr[32] | ncnt[N] | noff[N+1] | bsum[256] | sorted[E] | arr[E] | Wt | Sb | msgs
    int* ncnt   = ws + 32;
    int* noff   = ncnt + N;
    int* bsum   = noff + N + 1;
    int* sorted = bsum + 256;
    int* arr    = sorted + E;
    size_t intsEnd = (size_t)(32 + N + (N + 1) + 256 + 2 * (size_t)E) * sizeof(int);
    size_t wtOff   = (intsEnd + 255) & ~(size_t)255;
    size_t sbOff   = ((wtOff + (size_t)NTYPES * HID * 256 * 2) + 255) & ~(size_t)255;
    size_t msgs2Off= ((sbOff + (size_t)N * HID * 2) + 255) & ~(size_t)255;
    size_t need2   = msgs2Off + (size_t)E * HID * 2;
    size_t msgs1Off= sbOff;                       // MODE1: msgs where Sb would be
    size_t need1   = msgs1Off + (size_t)E * HID * 2;

    const int nb1 = (N + 1023) / 1024;
    const int nblocks = (E + E_TILE - 1) / E_TILE + NTYPES;
    const int eb = (E + 255) / 256;
    ushort* Wt = (ushort*)((char*)d_ws + wtOff);

    const int mode = (ws_size >= need2 && nb1 <= 256) ? 2
                   : (ws_size >= need1 && nb1 <= 256) ? 1 : 0;

    if (mode == 2) {
        ushort* Sb   = (ushort*)((char*)d_ws + sbOff);
        ushort* msgs = (ushort*)((char*)d_ws + msgs2Off);
        const int total = N * HID;
        const int sblocks = (total / 8 + 255) / 256;
        const int wblocks = (NTYPES * HID * 32 + 255) / 256;

        hipMemsetAsync(ws, 0, (size_t)(32 + N) * sizeof(int), stream);
        k_pass1<<<eb, 256, 0, stream>>>(etype, tgt, E, ws, ncnt, arr);
        k_prefix<<<1, 1, 0, stream>>>(ws);
        k_fill<<<eb, 256, 0, stream>>>(etype, E, ws, sorted);
        k_scan1<<<nb1, 256, 0, stream>>>(ncnt, noff, bsum, N);
        k_scan2<<<1, 256, 0, stream>>>(bsum, nb1);
        k_scan3<<<(N + 255) / 256, 256, 0, stream>>>(noff, bsum, N, E);
        k_conv<<<sblocks + wblocks, 256, 0, stream>>>(Sf, Sb, total, W, Wt, sblocks);
        k_edge_gemm<2><<<nblocks, 256, 0, stream>>>(Sf, Sb, src, tgt, Wt, ws, sorted,
                                                    noff, arr, msgs, out);
        k_scatter<<<(N + 3) / 4, 256, 0, stream>>>(msgs, noff, out, N);
    } else if (mode == 1) {
        ushort* msgs = (ushort*)((char*)d_ws + msgs1Off);

        hipMemsetAsync(ws, 0, (size_t)(32 + N) * sizeof(int), stream);
        k_pass1<<<eb, 256, 0, stream>>>(etype, tgt, E, ws, ncnt, arr);
        k_prefix<<<1, 1, 0, stream>>>(ws);
        k_fill<<<eb, 256, 0, stream>>>(etype, E, ws, sorted);
        k_scan1<<<nb1, 256, 0, stream>>>(ncnt, noff, bsum, N);
        k_scan2<<<1, 256, 0, stream>>>(bsum, nb1);
        k_scan3<<<(N + 255) / 256, 256, 0, stream>>>(noff, bsum, N, E);
        k_wconv<<<(NTYPES * HID * 32) / 256, 256, 0, stream>>>(W, Wt);
        k_edge_gemm<1><<<nblocks, 256, 0, stream>>>(Sf, nullptr, src, tgt, Wt, ws, sorted,
                                                    noff, arr, msgs, out);
        k_scatter<<<(N + 3) / 4, 256, 0, stream>>>(msgs, noff, out, N);
    } else {
        hipMemsetAsync(ws, 0, 32 * sizeof(int), stream);
        hipMemsetAsync(d_out, 0, (size_t)out_size * sizeof(float), stream);
        k_hist<<<eb, 256, 0, stream>>>(etype, E, ws);
        k_prefix<<<1, 1, 0, stream>>>(ws);
        k_fill<<<eb, 256, 0, stream>>>(etype, E, ws, sorted);
        k_wconv<<<(NTYPES * HID * 32) / 256, 256, 0, stream>>>(W, Wt);
        k_edge_gemm<0><<<nblocks, 256, 0, stream>>>(Sf, nullptr, src, tgt, Wt, ws, sorted,
                                                    nullptr, nullptr, nullptr, out);
    }
}

// Round 6
// 164.878 us; speedup vs baseline: 1.0509x; 1.0509x over previous
//
#include <hip/hip_runtime.h>

#define NTYPES 6
#define HID 128
#define E_TILE 64

typedef short short8 __attribute__((ext_vector_type(8)));
typedef float f32x4 __attribute__((ext_vector_type(4)));

static __device__ __forceinline__ ushort f2bf(float f) {
    union { float f; unsigned u; } v; v.f = f;
    unsigned r = v.u + 0x7FFFu + ((v.u >> 16) & 1u);   // RNE
    return (ushort)(r >> 16);
}

// ws layout: hdr[32] | ncnt[N] | noff[N+1] | bsum[256] | sorted[E] | arr[E] | Wt | Sb | msgs

// grid-stride int4 zero (replaces pathologically slow small hipMemsetAsync)
__global__ void k_zero(int4* __restrict__ p, int n4) {
    int i = blockIdx.x * blockDim.x + threadIdx.x;
    if (i < n4) p[i] = make_int4(0, 0, 0, 0);
}

// fused: per-block LDS type histogram + per-tgt-node arrival rank
__global__ void k_pass1(const int* __restrict__ etype, const int* __restrict__ tgt,
                        int E, int* __restrict__ cnts,
                        int* __restrict__ ncnt, int* __restrict__ arr) {
    __shared__ int h[NTYPES];
    if (threadIdx.x < NTYPES) h[threadIdx.x] = 0;
    __syncthreads();
    int i = blockIdx.x * blockDim.x + threadIdx.x;
    if (i < E) {
        atomicAdd(&h[etype[i] - 1], 1);
        arr[i] = atomicAdd(&ncnt[tgt[i]], 1);
    }
    __syncthreads();
    if (threadIdx.x < NTYPES) {
        int c = h[threadIdx.x];
        if (c) atomicAdd(&cnts[threadIdx.x], c);
    }
}

// hist-only (atomic fallback path)
__global__ void k_hist(const int* __restrict__ etype, int E, int* __restrict__ cnts) {
    __shared__ int h[NTYPES];
    if (threadIdx.x < NTYPES) h[threadIdx.x] = 0;
    __syncthreads();
    int i = blockIdx.x * blockDim.x + threadIdx.x;
    if (i < E) atomicAdd(&h[etype[i] - 1], 1);
    __syncthreads();
    if (threadIdx.x < NTYPES) {
        int c = h[threadIdx.x];
        if (c) atomicAdd(&cnts[threadIdx.x], c);
    }
}

// type-sort fill; computes the 6-wide exclusive type prefix locally from cnts
__global__ void k_fill(const int* __restrict__ etype, int E, int* __restrict__ hdr,
                       int* __restrict__ sorted) {
    __shared__ int lcnt[NTYPES];
    __shared__ int lbase[NTYPES];
    __shared__ int offl[NTYPES];
    if (threadIdx.x < NTYPES) lcnt[threadIdx.x] = 0;
    if (threadIdx.x == 0) {
        int acc = 0;
        for (int t = 0; t < NTYPES; ++t) { offl[t] = acc; acc += hdr[t]; }
    }
    __syncthreads();
    int i = blockIdx.x * blockDim.x + threadIdx.x;
    int t = 0, lr = 0;
    bool valid = (i < E);
    if (valid) {
        t = etype[i] - 1;
        lr = atomicAdd(&lcnt[t], 1);
    }
    __syncthreads();
    if (threadIdx.x < NTYPES) {
        int c = lcnt[threadIdx.x];
        lbase[threadIdx.x] = c ? atomicAdd(&hdr[16 + threadIdx.x], c) : 0;
    }
    __syncthreads();
    if (valid) sorted[offl[t] + lbase[t] + lr] = i;
}

// per-1024-chunk exclusive scan; bsum[b] = chunk total
__global__ void k_scan1(const int* __restrict__ ncnt, int* __restrict__ noff,
                        int* __restrict__ bsum, int N) {
    __shared__ int s[256];
    const int b = blockIdx.x, t = threadIdx.x;
    const int base = b * 1024 + t * 4;
    int v[4];
    #pragma unroll
    for (int i = 0; i < 4; ++i) v[i] = (base + i < N) ? ncnt[base + i] : 0;
    int tsum = v[0] + v[1] + v[2] + v[3];
    s[t] = tsum;
    __syncthreads();
    for (int off = 1; off < 256; off <<= 1) {
        int x = (t >= off) ? s[t - off] : 0;
        __syncthreads();
        s[t] += x;
        __syncthreads();
    }
    if (t == 255) bsum[b] = s[255];
    int run = s[t] - tsum;
    #pragma unroll
    for (int i = 0; i < 4; ++i)
        if (base + i < N) { noff[base + i] = run; run += v[i]; }
}

// exclusive scan over chunk totals (consumers add bsum[n>>10] themselves)
__global__ void k_scan2(int* __restrict__ bsum, int nb) {
    __shared__ int s[256];
    const int t = threadIdx.x;
    int v = (t < nb) ? bsum[t] : 0;
    s[t] = v;
    __syncthreads();
    for (int off = 1; off < 256; off <<= 1) {
        int x = (t >= off) ? s[t - off] : 0;
        __syncthreads();
        s[t] += x;
        __syncthreads();
    }
    if (t < nb) bsum[t] = s[t] - v;   // exclusive
}

// fused: state f32->bf16 copy + W transpose/convert
__global__ void k_conv(const float* __restrict__ Sf, ushort* __restrict__ Sb, int total,
                       const float* __restrict__ W, ushort* __restrict__ Wt, int sblocks) {
    int b = blockIdx.x;
    if (b < sblocks) {
        int g = (b * 256 + threadIdx.x) * 8;
        if (g < total) {
            float4 a = *(const float4*)(Sf + g);
            float4 c = *(const float4*)(Sf + g + 4);
            ushort t[8] = { f2bf(a.x), f2bf(a.y), f2bf(a.z), f2bf(a.w),
                            f2bf(c.x), f2bf(c.y), f2bf(c.z), f2bf(c.w) };
            *(short8*)(Sb + g) = *(short8*)t;
        }
    } else {
        int t = (b - sblocks) * 256 + threadIdx.x;
        int n  = t & 127;
        int k8 = (t >> 7) & 31;
        int ty = t >> 12;
        if (ty >= NTYPES) return;
        const float* wp = W + ((size_t)ty * 256 + (size_t)k8 * 8) * HID + n;
        ushort tmp[8];
        #pragma unroll
        for (int j = 0; j < 8; ++j) tmp[j] = f2bf(wp[(size_t)j * HID]);
        *(short8*)(Wt + ((size_t)ty * HID + n) * 256 + k8 * 8) = *(short8*)tmp;
    }
}

// W-only conversion (fallback paths)
__global__ void k_wconv(const float* __restrict__ W, ushort* __restrict__ Wt) {
    int t = blockIdx.x * blockDim.x + threadIdx.x;
    int n  = t & 127;
    int k8 = (t >> 7) & 31;
    int ty = t >> 12;
    if (ty >= NTYPES) return;
    const float* wp = W + ((size_t)ty * 256 + (size_t)k8 * 8) * HID + n;
    ushort tmp[8];
    #pragma unroll
    for (int j = 0; j < 8; ++j) tmp[j] = f2bf(wp[(size_t)j * HID]);
    *(short8*)(Wt + ((size_t)ty * HID + n) * 256 + k8 * 8) = *(short8*)tmp;
}

// ---------------- GEMM ----------------
// MODE 2: bf16 state gather, msgs write (no atomics)
// MODE 1: f32 state gather, msgs write (no atomics)
// MODE 0: f32 state gather, atomic scatter into out
template <int MODE>
__launch_bounds__(256, 4)
__global__ void k_edge_gemm(const float* __restrict__ Sf,
                            const ushort* __restrict__ Sb,
                            const int* __restrict__ src,
                            const int* __restrict__ tgt,
                            const ushort* __restrict__ Wt,
                            const int* __restrict__ hdr,
                            const int* __restrict__ sorted,
                            const int* __restrict__ noff,
                            const int* __restrict__ bsum,
                            const int* __restrict__ arr,
                            ushort* __restrict__ msgs,
                            float* __restrict__ out) {
    __shared__ __align__(16) ushort Xs[E_TILE][264];   // 33792 B
    __shared__ int sN[E_TILE];
    __shared__ int tN[E_TILE];
    __shared__ int dstR[E_TILE];

    // map blockIdx -> (type, tile-within-type); prefix computed from counts
    int tile = blockIdx.x;
    int ty, base = 0, cnt = 0, acc0 = 0;
    for (ty = 0; ty < NTYPES; ++ty) {
        int c = hdr[ty];
        int nt = (c + E_TILE - 1) / E_TILE;
        if (tile < nt) {
            base = acc0 + tile * E_TILE;
            cnt = c - tile * E_TILE;
            if (cnt > E_TILE) cnt = E_TILE;
            break;
        }
        tile -= nt; acc0 += c;
    }
    if (ty == NTYPES) return;

    const int tid = threadIdx.x;
    const int w  = tid >> 6;
    const int l  = tid & 63;
    const int lr = l & 15;
    const int lg = l >> 4;

    if (tid < E_TILE) {
        int sn = 0, tn = 0, dr = 0;
        if (tid < cnt) {
            int e = sorted[base + tid];
            sn = src[e]; tn = tgt[e];
            if (MODE >= 1) dr = noff[tn] + bsum[tn >> 10] + arr[e];
        }
        sN[tid] = sn; tN[tid] = tn; dstR[tid] = dr;
    }

    // prefetch all W fragments for this wave into registers
    short8 wreg[16];
    {
        const ushort* wb = Wt + ((size_t)ty * HID + w * 32 + lr) * 256 + 8 * lg;
        #pragma unroll
        for (int kk = 0; kk < 8; ++kk) {
            wreg[2 * kk]     = *(const short8*)(wb + kk * 32);
            wreg[2 * kk + 1] = *(const short8*)(wb + 16 * 256 + kk * 32);
        }
    }
    __syncthreads();

    // ---- stage X = [state[src] | state[tgt]] as bf16 [64][256] ----
    if (MODE == 2) {
        const int e = tid >> 2, q = tid & 3;           // 4 threads/edge, 64 ushorts each
        if (e < cnt) {
            const int node = (q & 2) ? tN[e] : sN[e];
            const ushort* rp = Sb + (size_t)node * HID + (q & 1) * 64;
            short8 v[8];
            #pragma unroll
            for (int i = 0; i < 8; ++i) v[i] = *(const short8*)(rp + i * 8);
            ushort* dp = &Xs[e][q * 64];
            #pragma unroll
            for (int i = 0; i < 8; ++i) *(short8*)(dp + i * 8) = v[i];
        } else {
            short8 z = (short8){0, 0, 0, 0, 0, 0, 0, 0};
            ushort* dp = &Xs[e][q * 64];
            #pragma unroll
            for (int i = 0; i < 8; ++i) *(short8*)(dp + i * 8) = z;
        }
    } else {
        const int e = tid >> 2, q = tid & 3;
        if (e < cnt) {
            #pragma unroll
            for (int h = 0; h < 2; ++h) {
                const int node = h ? tN[e] : sN[e];
                const float* rp = Sf + (size_t)node * HID + q * 32;
                #pragma unroll
                for (int i = 0; i < 4; ++i) {
                    float4 v0 = *(const float4*)(rp + i * 8);
                    float4 v1 = *(const float4*)(rp + i * 8 + 4);
                    ushort tmp[8] = { f2bf(v0.x), f2bf(v0.y), f2bf(v0.z), f2bf(v0.w),
                                      f2bf(v1.x), f2bf(v1.y), f2bf(v1.z), f2bf(v1.w) };
                    *(short8*)&Xs[e][h * HID + q * 32 + i * 8] = *(short8*)tmp;
                }
            }
        } else {
            short8 z = (short8){0, 0, 0, 0, 0, 0, 0, 0};
            #pragma unroll
            for (int h = 0; h < 2; ++h)
                #pragma unroll
                for (int i = 0; i < 4; ++i)
                    *(short8*)&Xs[e][h * HID + q * 32 + i * 8] = z;
        }
    }
    __syncthreads();

    f32x4 acc[4][2];
    #pragma unroll
    for (int mf = 0; mf < 4; ++mf)
        #pragma unroll
        for (int nf = 0; nf < 2; ++nf)
            acc[mf][nf] = (f32x4){0.f, 0.f, 0.f, 0.f};

    const ushort* xb = &Xs[lr][8 * lg];
    #pragma unroll
    for (int kk = 0; kk < 8; ++kk) {
        const int k0 = kk * 32;
        #pragma unroll
        for (int mf = 0; mf < 4; ++mf) {
            short8 a = *(const short8*)(xb + mf * 16 * 264 + k0);
            acc[mf][0] = __builtin_amdgcn_mfma_f32_16x16x32_bf16(a, wreg[2 * kk],     acc[mf][0], 0, 0, 0);
            acc[mf][1] = __builtin_amdgcn_mfma_f32_16x16x32_bf16(a, wreg[2 * kk + 1], acc[mf][1], 0, 0, 0);
        }
    }

    // ---- epilogue ----
    __syncthreads();
    float (*Os)[132] = (float (*)[132])&Xs[0][0];   // 64*132*4 = 33792 B exactly
    #pragma unroll
    for (int mf = 0; mf < 4; ++mf)
        #pragma unroll
        for (int nf = 0; nf < 2; ++nf)
            #pragma unroll
            for (int r = 0; r < 4; ++r)
                Os[mf * 16 + lg * 4 + r][w * 32 + nf * 16 + lr] = acc[mf][nf][r];
    __syncthreads();

    if (MODE >= 1) {
        const int r8 = tid >> 4, cg = tid & 15;
        #pragma unroll
        for (int rr = 0; rr < 4; ++rr) {
            int row = rr * 16 + r8;
            if (row < cnt) {
                float4 a = *(const float4*)&Os[row][cg * 8];
                float4 b = *(const float4*)&Os[row][cg * 8 + 4];
                ushort tmp[8] = { f2bf(a.x), f2bf(a.y), f2bf(a.z), f2bf(a.w),
                                  f2bf(b.x), f2bf(b.y), f2bf(b.z), f2bf(b.w) };
                *(short8*)(msgs + (size_t)dstR[row] * HID + cg * 8) = *(short8*)tmp;
            }
        }
    } else {
        const int erow = tid >> 7;
        const int c    = tid & (HID - 1);
        for (int it = 0; it < E_TILE / 2; ++it) {
            int ee = it * 2 + erow;
            if (ee < cnt) atomicAdd(&out[(size_t)tN[ee] * HID + c], Os[ee][c]);
        }
    }
}

// each 64-lane group owns one node: sum msgs rows, write out once
__launch_bounds__(256)
__global__ void k_scatter(const ushort* __restrict__ msgs, const int* __restrict__ noff,
                          const int* __restrict__ bsum, float* __restrict__ out,
                          int N, int Etot) {
    int node = blockIdx.x * 4 + (threadIdx.x >> 6);
    if (node >= N) return;
    int cp = threadIdx.x & 63;                 // column pair
    int s = noff[node] + bsum[node >> 10];
    int e = (node + 1 < N) ? (noff[node + 1] + bsum[(node + 1) >> 10]) : Etot;
    float a0 = 0.f, a1 = 0.f;
    for (int r = s; r < e; ++r) {
        unsigned u = *(const unsigned*)(msgs + (size_t)r * HID + cp * 2);
        union { unsigned u; float f; } lo, hi;
        lo.u = u << 16; hi.u = u & 0xFFFF0000u;
        a0 += lo.f; a1 += hi.f;
    }
    *(float2*)(out + (size_t)node * HID + cp * 2) = make_float2(a0, a1);
}

extern "C" void kernel_launch(void* const* d_in, const int* in_sizes, int n_in,
                              void* d_out, int out_size, void* d_ws, size_t ws_size,
                              hipStream_t stream) {
    const float* Sf    = (const float*)d_in[0];
    const int*   edges = (const int*)d_in[1];
    const float* W     = (const float*)d_in[2];
    float* out = (float*)d_out;

    const int E = in_sizes[1] / 3;
    const int N = in_sizes[0] / HID;
    const int* etype = edges;
    const int* src   = edges + E;
    const int* tgt   = edges + 2 * E;
    int* ws = (int*)d_ws;

    // layout: hdr[32] | ncnt[N] | noff[N+1] | bsum[256] | sorted[E] | arr[E] | Wt | Sb | msgs
    int* ncnt   = ws + 32;
    int* noff   = ncnt + N;
    int* bsum   = noff + N + 1;
    int* sorted = bsum + 256;
    int* arr    = sorted + E;
    size_t intsEnd = (size_t)(32 + N + (N + 1) + 256 + 2 * (size_t)E) * sizeof(int);
    size_t wtOff   = (intsEnd + 255) & ~(size_t)255;
    size_t sbOff   = ((wtOff + (size_t)NTYPES * HID * 256 * 2) + 255) & ~(size_t)255;
    size_t msgs2Off= ((sbOff + (size_t)N * HID * 2) + 255) & ~(size_t)255;
    size_t need2   = msgs2Off + (size_t)E * HID * 2;
    size_t msgs1Off= sbOff;                       // MODE1: msgs where Sb would be
    size_t need1   = msgs1Off + (size_t)E * HID * 2;

    const int nb1 = (N + 1023) / 1024;
    const int nblocks = (E + E_TILE - 1) / E_TILE + NTYPES;
    const int eb = (E + 255) / 256;
    ushort* Wt = (ushort*)((char*)d_ws + wtOff);

    const int mode = (ws_size >= need2 && nb1 <= 256) ? 2
                   : (ws_size >= need1 && nb1 <= 256) ? 1 : 0;

    if (mode >= 1) {
        const int n4 = (32 + N + 3) / 4;   // overshoot into noff is fine (written later)
        k_zero<<<(n4 + 255) / 256, 256, 0, stream>>>((int4*)ws, n4);
        k_pass1<<<eb, 256, 0, stream>>>(etype, tgt, E, ws, ncnt, arr);
        k_fill<<<eb, 256, 0, stream>>>(etype, E, ws, sorted);
        k_scan1<<<nb1, 256, 0, stream>>>(ncnt, noff, bsum, N);
        k_scan2<<<1, 256, 0, stream>>>(bsum, nb1);

        if (mode == 2) {
            ushort* Sb   = (ushort*)((char*)d_ws + sbOff);
            ushort* msgs = (ushort*)((char*)d_ws + msgs2Off);
            const int total = N * HID;
            const int sblocks = (total / 8 + 255) / 256;
            const int wblocks = (NTYPES * HID * 32 + 255) / 256;
            k_conv<<<sblocks + wblocks, 256, 0, stream>>>(Sf, Sb, total, W, Wt, sblocks);
            k_edge_gemm<2><<<nblocks, 256, 0, stream>>>(Sf, Sb, src, tgt, Wt, ws, sorted,
                                                        noff, bsum, arr, msgs, out);
            k_scatter<<<(N + 3) / 4, 256, 0, stream>>>(msgs, noff, bsum, out, N, E);
        } else {
            ushort* msgs = (ushort*)((char*)d_ws + msgs1Off);
            k_wconv<<<(NTYPES * HID * 32) / 256, 256, 0, stream>>>(W, Wt);
            k_edge_gemm<1><<<nblocks, 256, 0, stream>>>(Sf, nullptr, src, tgt, Wt, ws, sorted,
                                                        noff, bsum, arr, msgs, out);
            k_scatter<<<(N + 3) / 4, 256, 0, stream>>>(msgs, noff, bsum, out, N, E);
        }
    } else {
        k_zero<<<1, 64, 0, stream>>>((int4*)ws, 8);
        hipMemsetAsync(d_out, 0, (size_t)out_size * sizeof(float), stream);
        k_hist<<<eb, 256, 0, stream>>>(etype, E, ws);
        k_fill<<<eb, 256, 0, stream>>>(etype, E, ws, sorted);
        k_wconv<<<(NTYPES * HID * 32) / 256, 256, 0, stream>>>(W, Wt);
        k_edge_gemm<0><<<nblocks, 256, 0, stream>>>(Sf, nullptr, src, tgt, Wt, ws, sorted,
                                                    nullptr, nullptr, nullptr, nullptr, out);
    }
}